// Round 1
// baseline (529.284 us; speedup 1.0000x reference)
//
#include <hip/hip_runtime.h>
#include <cstdint>
#include <cstddef>

// x: [512][64][1024], conv1: K=32 S=16 -> T=63, Cout=256
// z layout: [n][t][c] flat = (n*63+t)*256 + c
// fp16 2-limb: v ~= hi + lo*(1/2048), hi=fp16(v), lo=fp16((v-hi)*2048)

typedef _Float16 half8 __attribute__((ext_vector_type(8)));
typedef float floatx4 __attribute__((ext_vector_type(4)));

__device__ __forceinline__ void split_f32(float v, _Float16& hi, _Float16& lo) {
    _Float16 h = (_Float16)v;
    hi = h;
    lo = (_Float16)((v - (float)h) * 2048.0f);
}

// ---------------------------------------------------------------------------
// K0: prep — BN fold, fp16 limb splits of conv1_w, conv2_w(T), w1 (dense1)
// ---------------------------------------------------------------------------
__global__ __launch_bounds__(256) void prep_kernel(
    const float* __restrict__ c1w, const float* __restrict__ c1b,
    const float* __restrict__ g1,  const float* __restrict__ b1,
    const float* __restrict__ m1,  const float* __restrict__ v1,
    const float* __restrict__ c2w, const float* __restrict__ c2b,
    const float* __restrict__ g2,  const float* __restrict__ b2,
    const float* __restrict__ m2,  const float* __restrict__ v2,
    const float* __restrict__ w1,
    _Float16* __restrict__ w1h, _Float16* __restrict__ w1l,
    _Float16* __restrict__ w2h, _Float16* __restrict__ w2l,
    _Float16* __restrict__ wdh, _Float16* __restrict__ wdl,
    float* __restrict__ ab1, float* __restrict__ ab2)
{
    const int id = blockIdx.x * 256 + threadIdx.x;   // 65536 total
    if (id < 256) {
        float a1 = g1[id] / sqrtf(v1[id] + 1e-5f);
        ab1[id]       = a1;
        ab1[256 + id] = (c1b[id] - m1[id]) * a1 + b1[id];
        float a2 = g2[id] / sqrtf(v2[id] + 1e-5f);
        ab2[id]       = a2;
        ab2[256 + id] = (c2b[id] - m2[id]) * a2 + b2[id];
    }
    // dense1 weights: w1[o][c] row-major already == B-row layout [o][k=c]
    split_f32(w1[id], wdh[id], wdl[id]);
    // conv1_w limbs: [o][2048] direct layout
    for (int idx = id; idx < 256 * 2048; idx += 65536)
        split_f32(c1w[idx], w1h[idx], w1l[idx]);
    // conv2_w limbs transposed to [o][dt*256+c]
    for (int idx = id; idx < 256 * 768; idx += 65536) {
        const int o  = idx / 768;
        const int r  = idx - o * 768;
        const int dt = r >> 8;
        const int c  = r & 255;
        split_f32(c2w[o * 768 + c * 3 + dt], w2h[idx], w2l[idx]);
    }
}

// ---------------------------------------------------------------------------
// K1: conv1 + bn1, fp16 2-limb MFMA GEMM. M=32256, K=2048 (c*32+k), N=256.
// BM=64, BN=128 tile; 4 waves in 2x2 grid, per-wave 32x64; acc = 64 AGPRs.
// Grid (504,2) = 1008 blocks -> ~3 blocks/CU resident (was 2) for latency hiding.
// Numerically bit-identical to the previous 128x128 version.
// ---------------------------------------------------------------------------
__global__ __launch_bounds__(256, 3) void conv1_mfma(
    const float* __restrict__ x,
    const _Float16* __restrict__ w1h, const _Float16* __restrict__ w1l,
    const float* __restrict__ ab,
    _Float16* __restrict__ z1h, _Float16* __restrict__ z1l)
{
    __shared__ _Float16 Ah[4][64][8];    // [k-chunk][m][8] fragment-major
    __shared__ _Float16 Al[4][64][8];
    __shared__ _Float16 Bh[4][128][8];
    __shared__ _Float16 Bl[4][128][8];

    const int tid = threadIdx.x;
    const int bm = blockIdx.x, bn = blockIdx.y;

    // A staging role: 64 rows x 32 k per iter; 8 floats/thread
    const int ar = tid & 63;
    const int kc = tid >> 6;            // k-chunk 0..3 (8 elems each)
    const int am = bm * 64 + ar;
    const int an = am / 63, at = am - an * 63;
    const float* arow = x + (size_t)an * 65536 + at * 16 + kc * 8;

    // B staging role: 128 rows x 32 k per iter; 2 int4/limb/thread
    const int lr = tid & 127;
    const int h  = tid >> 7;
    const _Float16* bhrow = w1h + (size_t)(bn * 128 + lr) * 2048 + h * 16;
    const _Float16* blrow = w1l + (size_t)(bn * 128 + lr) * 2048 + h * 16;

    const int lane = tid & 63;
    const int wv   = tid >> 6;
    const int mw   = wv & 1, nw = wv >> 1;
    const int quad = lane >> 4;
    const int l15  = lane & 15;

    floatx4 accA[2][4] = {};
    floatx4 accB[2][4] = {};

    for (int it = 0; it < 64; ++it) {
        const float* ap = arow + it * 1024;
        float va[8];
        *(float4*)&va[0] = *(const float4*)(ap);
        *(float4*)&va[4] = *(const float4*)(ap + 4);
        int4 bh0 = *(const int4*)(bhrow + it * 32);
        int4 bh1 = *(const int4*)(bhrow + it * 32 + 8);
        int4 bl0 = *(const int4*)(blrow + it * 32);
        int4 bl1 = *(const int4*)(blrow + it * 32 + 8);

        union U { _Float16 hf[8]; int4 v; };
        U ch, cl;
#pragma unroll
        for (int j = 0; j < 8; ++j) split_f32(va[j], ch.hf[j], cl.hf[j]);

        __syncthreads();
        *(int4*)&Ah[kc][ar][0] = ch.v;
        *(int4*)&Al[kc][ar][0] = cl.v;
        *(int4*)&Bh[2*h  ][lr][0] = bh0;
        *(int4*)&Bh[2*h+1][lr][0] = bh1;
        *(int4*)&Bl[2*h  ][lr][0] = bl0;
        *(int4*)&Bl[2*h+1][lr][0] = bl1;
        __syncthreads();

        half8 fah[2], fal[2], fbh[4], fbl[4];
#pragma unroll
        for (int t = 0; t < 2; ++t) {
            fah[t] = *(const half8*)&Ah[quad][mw*32 + t*16 + l15][0];
            fal[t] = *(const half8*)&Al[quad][mw*32 + t*16 + l15][0];
        }
#pragma unroll
        for (int t = 0; t < 4; ++t) {
            fbh[t] = *(const half8*)&Bh[quad][nw*64 + t*16 + l15][0];
            fbl[t] = *(const half8*)&Bl[quad][nw*64 + t*16 + l15][0];
        }
#pragma unroll
        for (int ti = 0; ti < 2; ++ti)
#pragma unroll
            for (int tj = 0; tj < 4; ++tj) {
                accA[ti][tj] = __builtin_amdgcn_mfma_f32_16x16x32_f16(fah[ti], fbh[tj], accA[ti][tj], 0, 0, 0);
                accB[ti][tj] = __builtin_amdgcn_mfma_f32_16x16x32_f16(fah[ti], fbl[tj], accB[ti][tj], 0, 0, 0);
                accB[ti][tj] = __builtin_amdgcn_mfma_f32_16x16x32_f16(fal[ti], fbh[tj], accB[ti][tj], 0, 0, 0);
            }
    }

#pragma unroll
    for (int tj = 0; tj < 4; ++tj) {
        const int o = bn*128 + nw*64 + tj*16 + l15;
        const float alpha = ab[o], beta = ab[256 + o];
#pragma unroll
        for (int ti = 0; ti < 2; ++ti) {
            const int m0 = bm*64 + mw*32 + ti*16 + quad*4;
#pragma unroll
            for (int r = 0; r < 4; ++r) {
                float c = accA[ti][tj][r] + accB[ti][tj][r] * (1.0f/2048.0f);
                float z = c * alpha + beta;
                _Float16 zh, zl;
                split_f32(z, zh, zl);
                const size_t off = (size_t)(m0 + r) * 256 + o;
                z1h[off] = zh;
                z1l[off] = zl;
            }
        }
    }
}

// ---------------------------------------------------------------------------
// K2: conv2 + bn2, fp16 2-limb MFMA GEMM. K=768 (dt*256+c), halo zero-fill.
// Same BM=64 restructure as conv1.
// ---------------------------------------------------------------------------
__global__ __launch_bounds__(256, 3) void conv2_mfma(
    const _Float16* __restrict__ z1h, const _Float16* __restrict__ z1l,
    const _Float16* __restrict__ w2h, const _Float16* __restrict__ w2l,
    const float* __restrict__ ab, float* __restrict__ z2)
{
    __shared__ _Float16 Ah[4][64][8];
    __shared__ _Float16 Al[4][64][8];
    __shared__ _Float16 Bh[4][128][8];
    __shared__ _Float16 Bl[4][128][8];

    const int tid = threadIdx.x;
    const int bm = blockIdx.x, bn = blockIdx.y;

    const int ar = tid & 63;
    const int kc = tid >> 6;
    const int am = bm * 64 + ar;
    const int an = am / 63, at = am - an * 63;
    const _Float16* abase_h = z1h + (size_t)an * 16128;
    const _Float16* abase_l = z1l + (size_t)an * 16128;

    const int lr = tid & 127;
    const int h  = tid >> 7;
    const _Float16* bhrow = w2h + (size_t)(bn * 128 + lr) * 768 + h * 16;
    const _Float16* blrow = w2l + (size_t)(bn * 128 + lr) * 768 + h * 16;

    const int lane = tid & 63;
    const int wv   = tid >> 6;
    const int mw   = wv & 1, nw = wv >> 1;
    const int quad = lane >> 4;
    const int l15  = lane & 15;

    floatx4 accA[2][4] = {};
    floatx4 accB[2][4] = {};

    const int4 z4 = {0, 0, 0, 0};

    for (int it = 0; it < 24; ++it) {
        const int kap0 = it * 32;
        const int dt   = kap0 >> 8;
        const int c0   = kap0 & 255;
        const int trow = at + dt - 1;
        const bool valid = (trow >= 0) && (trow < 63);
        const _Float16* aph = abase_h + trow * 256 + c0 + kc * 8;
        const _Float16* apl = abase_l + trow * 256 + c0 + kc * 8;
        int4 a_h = valid ? *(const int4*)(aph) : z4;
        int4 a_l = valid ? *(const int4*)(apl) : z4;
        int4 b0h = *(const int4*)(bhrow + kap0);
        int4 b1h = *(const int4*)(bhrow + kap0 + 8);
        int4 b0l = *(const int4*)(blrow + kap0);
        int4 b1l = *(const int4*)(blrow + kap0 + 8);

        __syncthreads();
        *(int4*)&Ah[kc][ar][0] = a_h;
        *(int4*)&Al[kc][ar][0] = a_l;
        *(int4*)&Bh[2*h  ][lr][0] = b0h;
        *(int4*)&Bh[2*h+1][lr][0] = b1h;
        *(int4*)&Bl[2*h  ][lr][0] = b0l;
        *(int4*)&Bl[2*h+1][lr][0] = b1l;
        __syncthreads();

        half8 fah[2], fal[2], fbh[4], fbl[4];
#pragma unroll
        for (int t = 0; t < 2; ++t) {
            fah[t] = *(const half8*)&Ah[quad][mw*32 + t*16 + l15][0];
            fal[t] = *(const half8*)&Al[quad][mw*32 + t*16 + l15][0];
        }
#pragma unroll
        for (int t = 0; t < 4; ++t) {
            fbh[t] = *(const half8*)&Bh[quad][nw*64 + t*16 + l15][0];
            fbl[t] = *(const half8*)&Bl[quad][nw*64 + t*16 + l15][0];
        }
#pragma unroll
        for (int ti = 0; ti < 2; ++ti)
#pragma unroll
            for (int tj = 0; tj < 4; ++tj) {
                accA[ti][tj] = __builtin_amdgcn_mfma_f32_16x16x32_f16(fah[ti], fbh[tj], accA[ti][tj], 0, 0, 0);
                accB[ti][tj] = __builtin_amdgcn_mfma_f32_16x16x32_f16(fah[ti], fbl[tj], accB[ti][tj], 0, 0, 0);
                accB[ti][tj] = __builtin_amdgcn_mfma_f32_16x16x32_f16(fal[ti], fbh[tj], accB[ti][tj], 0, 0, 0);
            }
    }

#pragma unroll
    for (int tj = 0; tj < 4; ++tj) {
        const int o = bn*128 + nw*64 + tj*16 + l15;
        const float alpha = ab[o], beta = ab[256 + o];
#pragma unroll
        for (int ti = 0; ti < 2; ++ti) {
            const int m0 = bm*64 + mw*32 + ti*16 + quad*4;
#pragma unroll
            for (int r = 0; r < 4; ++r) {
                float c = accA[ti][tj][r] + accB[ti][tj][r] * (1.0f/2048.0f);
                z2[(size_t)(m0 + r) * 256 + o] = c * alpha + beta;
            }
        }
    }
}

// ---------------------------------------------------------------------------
// K3a: cuba1 — z2 [n][t][c] -> binary spikes s1 (fp16 {0,1}) in [n][t][c]
// ---------------------------------------------------------------------------
__global__ __launch_bounds__(256) void cuba1_kernel(
    const float* __restrict__ z2, _Float16* __restrict__ s1)
{
    const int n   = blockIdx.x;
    const int tid = threadIdx.x;
    const float* zrow = z2 + (size_t)n * 16128 + tid;
    _Float16*    srow = s1 + (size_t)n * 16128 + tid;
    float cur = 0.f, vol = 0.f;
    for (int t = 0; t < 63; ++t) {
        float xv = zrow[(size_t)t * 256];
        cur = 0.1f * cur + xv;
        vol = 0.1f * vol + cur;
        bool sp = (vol - 0.3f) >= 0.f;
        srow[(size_t)t * 256] = sp ? (_Float16)1.0f : (_Float16)0.0f;
        if (sp) vol = 0.f;
    }
}

// ---------------------------------------------------------------------------
// K3b: dense1 via MFMA. M=32256, K=256, N=256. A binary fp16 (1 limb), B 2-limb.
// Same BM=64 restructure.
// ---------------------------------------------------------------------------
__global__ __launch_bounds__(256, 3) void dense1_mfma(
    const _Float16* __restrict__ s1,
    const _Float16* __restrict__ wdh, const _Float16* __restrict__ wdl,
    float* __restrict__ y1)
{
    __shared__ _Float16 As[4][64][8];
    __shared__ _Float16 Bh[4][128][8];
    __shared__ _Float16 Bl[4][128][8];

    const int tid = threadIdx.x;
    const int bm = blockIdx.x, bn = blockIdx.y;

    const int ar = tid & 63;
    const int kc = tid >> 6;
    const _Float16* arow = s1 + (size_t)(bm * 64 + ar) * 256 + kc * 8;

    const int lr = tid & 127;
    const int h  = tid >> 7;
    const _Float16* bhrow = wdh + (size_t)(bn * 128 + lr) * 256 + h * 16;
    const _Float16* blrow = wdl + (size_t)(bn * 128 + lr) * 256 + h * 16;

    const int lane = tid & 63;
    const int wv   = tid >> 6;
    const int mw   = wv & 1, nw = wv >> 1;
    const int quad = lane >> 4;
    const int l15  = lane & 15;

    floatx4 accA[2][4] = {};
    floatx4 accB[2][4] = {};

    for (int it = 0; it < 8; ++it) {
        const int kap0 = it * 32;
        int4 a0 = *(const int4*)(arow + kap0);
        int4 b0h = *(const int4*)(bhrow + kap0);
        int4 b1h = *(const int4*)(bhrow + kap0 + 8);
        int4 b0l = *(const int4*)(blrow + kap0);
        int4 b1l = *(const int4*)(blrow + kap0 + 8);

        __syncthreads();
        *(int4*)&As[kc][ar][0] = a0;
        *(int4*)&Bh[2*h  ][lr][0] = b0h;
        *(int4*)&Bh[2*h+1][lr][0] = b1h;
        *(int4*)&Bl[2*h  ][lr][0] = b0l;
        *(int4*)&Bl[2*h+1][lr][0] = b1l;
        __syncthreads();

        half8 fa[2], fbh[4], fbl[4];
#pragma unroll
        for (int t = 0; t < 2; ++t)
            fa[t]  = *(const half8*)&As[quad][mw*32 + t*16 + l15][0];
#pragma unroll
        for (int t = 0; t < 4; ++t) {
            fbh[t] = *(const half8*)&Bh[quad][nw*64 + t*16 + l15][0];
            fbl[t] = *(const half8*)&Bl[quad][nw*64 + t*16 + l15][0];
        }
#pragma unroll
        for (int ti = 0; ti < 2; ++ti)
#pragma unroll
            for (int tj = 0; tj < 4; ++tj) {
                accA[ti][tj] = __builtin_amdgcn_mfma_f32_16x16x32_f16(fa[ti], fbh[tj], accA[ti][tj], 0, 0, 0);
                accB[ti][tj] = __builtin_amdgcn_mfma_f32_16x16x32_f16(fa[ti], fbl[tj], accB[ti][tj], 0, 0, 0);
            }
    }

#pragma unroll
    for (int tj = 0; tj < 4; ++tj) {
        const int o = bn*128 + nw*64 + tj*16 + l15;
#pragma unroll
        for (int ti = 0; ti < 2; ++ti) {
            const int m0 = bm*64 + mw*32 + ti*16 + quad*4;
#pragma unroll
            for (int r = 0; r < 4; ++r)
                y1[(size_t)(m0 + r) * 256 + o] =
                    accA[ti][tj][r] + accB[ti][tj][r] * (1.0f/2048.0f);
        }
    }
}

// ---------------------------------------------------------------------------
// K3c: cuba2 (per (n,o) over t) -> spike masks -> dense2 -> cuba3 -> out
// ---------------------------------------------------------------------------
__global__ __launch_bounds__(256) void snn_tail(
    const float* __restrict__ y1, const float* __restrict__ w2,
    float* __restrict__ out)
{
    __shared__ unsigned long long M2[256];
    __shared__ float Y[2 * 63];
    const int n   = blockIdx.x;
    const int tid = threadIdx.x;

    {
        const float* yrow = y1 + (size_t)n * 16128 + tid;
        float v = 0.f;
        unsigned long long mask2 = 0ull;
        for (int t = 0; t < 63; ++t) {
            float yv = yrow[(size_t)t * 256];
            v = 0.9f * v + yv;                 // cd=0 -> i = x
            if ((v - 0.1f) >= 0.f) { mask2 |= (1ull << t); v = 0.f; }
        }
        M2[tid] = mask2;
    }
    __syncthreads();

    if (tid < 126) {
        const int cls = tid / 63;
        const int t   = tid - cls * 63;
        const float* wrow = w2 + cls * 256;
        float acc = 0.f;
#pragma unroll 4
        for (int o = 0; o < 256; ++o)
            acc += ((M2[o] >> t) & 1ull) ? wrow[o] : 0.f;
        Y[cls * 63 + t] = acc;
    }
    __syncthreads();
    if (tid < 2) {
        float v = 0.f;
        float* orow = out + (size_t)n * 126 + tid * 63;
        for (int t = 0; t < 63; ++t) {
            v = 0.9f * v + Y[tid * 63 + t];
            float u = v - 0.1f;
            float s = (u >= 0.f) ? 1.f : 0.f;
            orow[t] = s;
            v = (u >= 0.f) ? 0.f : v;
        }
    }
}

// ---------------------------------------------------------------------------
extern "C" void kernel_launch(void* const* d_in, const int* in_sizes, int n_in,
                              void* d_out, int out_size, void* d_ws, size_t ws_size,
                              hipStream_t stream)
{
    const float* x    = (const float*)d_in[0];
    const float* c1w  = (const float*)d_in[1];
    const float* c1b  = (const float*)d_in[2];
    const float* g1   = (const float*)d_in[3];
    const float* b1   = (const float*)d_in[4];
    const float* m1   = (const float*)d_in[5];
    const float* v1   = (const float*)d_in[6];
    const float* c2w  = (const float*)d_in[7];
    const float* c2b  = (const float*)d_in[8];
    const float* g2   = (const float*)d_in[9];
    const float* b2   = (const float*)d_in[10];
    const float* m2   = (const float*)d_in[11];
    const float* v2   = (const float*)d_in[12];
    const float* w1   = (const float*)d_in[13];
    const float* w2   = (const float*)d_in[14];
    float* out = (float*)d_out;

    float* ws = (float*)d_ws;
    // region A: z1 limbs during conv; reused as y1 (fp32) after conv2
    float*    zA  = ws;                               // 8,257,536 f
    _Float16* z1h = (_Float16*)zA;
    _Float16* z1l = (_Float16*)(zA + 4128768);
    float*    y1  = zA;
    float*    z2  = zA + 8257536;                     // 8,257,536 f
    _Float16* s1  = (_Float16*)(z2 + 8257536);        // 4,128,768 f
    float*    wsp = z2 + 8257536 + 4128768;
    _Float16* w1h = (_Float16*)wsp;                   // 262,144 f
    _Float16* w1l = (_Float16*)(wsp + 262144);        // 262,144 f
    _Float16* w2h = (_Float16*)(wsp + 2*262144);                    //  98,304 f
    _Float16* w2l = (_Float16*)(wsp + 2*262144 + 98304);            //  98,304 f
    _Float16* wdh = (_Float16*)(wsp + 2*262144 + 2*98304);          //  32,768 f
    _Float16* wdl = (_Float16*)(wsp + 2*262144 + 2*98304 + 32768);  //  32,768 f
    float*    ab1 = wsp + 2*262144 + 2*98304 + 2*32768;
    float*    ab2 = ab1 + 512;

    prep_kernel<<<256, 256, 0, stream>>>(c1w, c1b, g1, b1, m1, v1,
                                         c2w, c2b, g2, b2, m2, v2,
                                         w1, w1h, w1l, w2h, w2l, wdh, wdl,
                                         ab1, ab2);
    conv1_mfma<<<dim3(504, 2), 256, 0, stream>>>(x, w1h, w1l, ab1, z1h, z1l);
    conv2_mfma<<<dim3(504, 2), 256, 0, stream>>>(z1h, z1l, w2h, w2l, ab2, z2);
    cuba1_kernel<<<512, 256, 0, stream>>>(z2, s1);
    dense1_mfma<<<dim3(504, 2), 256, 0, stream>>>(s1, wdh, wdl, y1);
    snn_tail<<<512, 256, 0, stream>>>(y1, w2, out);
}

// Round 2
// 449.653 us; speedup vs baseline: 1.1771x; 1.1771x over previous
//
#include <hip/hip_runtime.h>
#include <cstdint>
#include <cstddef>

// x: [512][64][1024], conv1: K=32 S=16 -> T=63, Cout=256
// z layout: [n][t][c] flat = (n*63+t)*256 + c
// fp16 2-limb: v ~= hi + lo*(1/2048), hi=fp16(v), lo=fp16((v-hi)*2048)

typedef _Float16 half8 __attribute__((ext_vector_type(8)));
typedef float floatx4 __attribute__((ext_vector_type(4)));

__device__ __forceinline__ void split_f32(float v, _Float16& hi, _Float16& lo) {
    _Float16 h = (_Float16)v;
    hi = h;
    lo = (_Float16)((v - (float)h) * 2048.0f);
}

// global -> LDS direct DMA, 16B per lane (wave-uniform LDS base + lane*16)
typedef const __attribute__((address_space(1))) unsigned int* gas_ptr;
typedef __attribute__((address_space(3))) unsigned int* las_ptr;
__device__ __forceinline__ void lds_dma16(const void* g, void* l) {
    __builtin_amdgcn_global_load_lds((gas_ptr)g, (las_ptr)l, 16, 0, 0);
}

// ---------------------------------------------------------------------------
// K0: prep — BN fold, fp16 limb splits of conv1_w, conv2_w(T), w1 (dense1)
// ---------------------------------------------------------------------------
__global__ __launch_bounds__(256) void prep_kernel(
    const float* __restrict__ c1w, const float* __restrict__ c1b,
    const float* __restrict__ g1,  const float* __restrict__ b1,
    const float* __restrict__ m1,  const float* __restrict__ v1,
    const float* __restrict__ c2w, const float* __restrict__ c2b,
    const float* __restrict__ g2,  const float* __restrict__ b2,
    const float* __restrict__ m2,  const float* __restrict__ v2,
    const float* __restrict__ w1,
    _Float16* __restrict__ w1h, _Float16* __restrict__ w1l,
    _Float16* __restrict__ w2h, _Float16* __restrict__ w2l,
    _Float16* __restrict__ wdh, _Float16* __restrict__ wdl,
    float* __restrict__ ab1, float* __restrict__ ab2)
{
    const int id = blockIdx.x * 256 + threadIdx.x;   // 65536 total
    if (id < 256) {
        float a1 = g1[id] / sqrtf(v1[id] + 1e-5f);
        ab1[id]       = a1;
        ab1[256 + id] = (c1b[id] - m1[id]) * a1 + b1[id];
        float a2 = g2[id] / sqrtf(v2[id] + 1e-5f);
        ab2[id]       = a2;
        ab2[256 + id] = (c2b[id] - m2[id]) * a2 + b2[id];
    }
    // dense1 weights: w1[o][c] row-major already == B-row layout [o][k=c]
    split_f32(w1[id], wdh[id], wdl[id]);
    // conv1_w limbs: [o][2048] direct layout
    for (int idx = id; idx < 256 * 2048; idx += 65536)
        split_f32(c1w[idx], w1h[idx], w1l[idx]);
    // conv2_w limbs transposed to [o][dt*256+c]
    for (int idx = id; idx < 256 * 768; idx += 65536) {
        const int o  = idx / 768;
        const int r  = idx - o * 768;
        const int dt = r >> 8;
        const int c  = r & 255;
        split_f32(c2w[o * 768 + c * 3 + dt], w2h[idx], w2l[idx]);
    }
}

// ---------------------------------------------------------------------------
// K1: conv1 + bn1, fp16 2-limb MFMA GEMM. M=32256, K=2048 (c*32+k), N=256.
// 128x128 tile, double-buffered LDS, ONE barrier per K-step.
// B limbs staged via global_load_lds DMA; A (fp32 x) reg-staged + split,
// with loads issued before the MFMA phase and ds_writes after (T14).
// ---------------------------------------------------------------------------
__global__ __launch_bounds__(256, 2) void conv1_mfma(
    const float* __restrict__ x,
    const _Float16* __restrict__ w1h, const _Float16* __restrict__ w1l,
    const float* __restrict__ ab,
    _Float16* __restrict__ z1h, _Float16* __restrict__ z1l)
{
    __shared__ _Float16 Ah[2][4][128][8];   // [buf][k-quad][m][8] fragment-major
    __shared__ _Float16 Al[2][4][128][8];
    __shared__ _Float16 Bh[2][4][128][8];
    __shared__ _Float16 Bl[2][4][128][8];

    const int tid = threadIdx.x;
    const int bm = blockIdx.x, bn = blockIdx.y;
    const int lr = tid & 127;
    const int h  = tid >> 7;

    const int am = bm * 128 + lr;
    const int an = am / 63, at = am - an * 63;
    const float* arow = x + (size_t)an * 65536 + at * 16 + h * 16;

    const int lane = tid & 63;
    const int wv   = tid >> 6;
    const int mw   = wv & 1, nw = wv >> 1;
    const int quad = lane >> 4;
    const int l15  = lane & 15;

    // B DMA assignment: wave wv stages quads {q0, q0+2} of row-half (wv&1)
    const int q0 = wv >> 1;
    const int rh = (wv & 1) * 64;
    const _Float16* bh_g = w1h + (size_t)(bn * 128 + rh + lane) * 2048;
    const _Float16* bl_g = w1l + (size_t)(bn * 128 + rh + lane) * 2048;

    floatx4 accA[4][4] = {};
    floatx4 accB[4][4] = {};

    union U { _Float16 hf[8]; int4 v; };
    float va[16];

    // ---- prologue: stage tile 0 into buf 0 ----
    {
        *(float4*)&va[0]  = *(const float4*)(arow);
        *(float4*)&va[4]  = *(const float4*)(arow + 4);
        *(float4*)&va[8]  = *(const float4*)(arow + 8);
        *(float4*)&va[12] = *(const float4*)(arow + 12);
        lds_dma16(bh_g + q0 * 8,       &Bh[0][q0    ][rh][0]);
        lds_dma16(bh_g + (q0 + 2) * 8, &Bh[0][q0 + 2][rh][0]);
        lds_dma16(bl_g + q0 * 8,       &Bl[0][q0    ][rh][0]);
        lds_dma16(bl_g + (q0 + 2) * 8, &Bl[0][q0 + 2][rh][0]);
        U c0h, c0l, c1h, c1l;
#pragma unroll
        for (int j = 0; j < 8; ++j) split_f32(va[j],     c0h.hf[j], c0l.hf[j]);
#pragma unroll
        for (int j = 0; j < 8; ++j) split_f32(va[8 + j], c1h.hf[j], c1l.hf[j]);
        *(int4*)&Ah[0][2*h  ][lr][0] = c0h.v;
        *(int4*)&Ah[0][2*h+1][lr][0] = c1h.v;
        *(int4*)&Al[0][2*h  ][lr][0] = c0l.v;
        *(int4*)&Al[0][2*h+1][lr][0] = c1l.v;
        __syncthreads();
    }

    int cur = 0;
    for (int it = 0; it < 64; ++it) {
        const int nxt = cur ^ 1;
        const bool pf = (it < 63);

        // issue next-tile loads (latency hides under this iteration's MFMAs)
        if (pf) {
            const float* ap = arow + (it + 1) * 1024;
            *(float4*)&va[0]  = *(const float4*)(ap);
            *(float4*)&va[4]  = *(const float4*)(ap + 4);
            *(float4*)&va[8]  = *(const float4*)(ap + 8);
            *(float4*)&va[12] = *(const float4*)(ap + 12);
            const int ko = (it + 1) * 32;
            lds_dma16(bh_g + ko + q0 * 8,       &Bh[nxt][q0    ][rh][0]);
            lds_dma16(bh_g + ko + (q0 + 2) * 8, &Bh[nxt][q0 + 2][rh][0]);
            lds_dma16(bl_g + ko + q0 * 8,       &Bl[nxt][q0    ][rh][0]);
            lds_dma16(bl_g + ko + (q0 + 2) * 8, &Bl[nxt][q0 + 2][rh][0]);
        }

        half8 fah[4], fal[4], fbh[4], fbl[4];
#pragma unroll
        for (int t = 0; t < 4; ++t) {
            fah[t] = *(const half8*)&Ah[cur][quad][mw*64 + t*16 + l15][0];
            fal[t] = *(const half8*)&Al[cur][quad][mw*64 + t*16 + l15][0];
            fbh[t] = *(const half8*)&Bh[cur][quad][nw*64 + t*16 + l15][0];
            fbl[t] = *(const half8*)&Bl[cur][quad][nw*64 + t*16 + l15][0];
        }
#pragma unroll
        for (int ti = 0; ti < 4; ++ti)
#pragma unroll
            for (int tj = 0; tj < 4; ++tj) {
                accA[ti][tj] = __builtin_amdgcn_mfma_f32_16x16x32_f16(fah[ti], fbh[tj], accA[ti][tj], 0, 0, 0);
                accB[ti][tj] = __builtin_amdgcn_mfma_f32_16x16x32_f16(fah[ti], fbl[tj], accB[ti][tj], 0, 0, 0);
                accB[ti][tj] = __builtin_amdgcn_mfma_f32_16x16x32_f16(fal[ti], fbh[tj], accB[ti][tj], 0, 0, 0);
            }

        // late A stage: split + ds_write into the other buffer
        if (pf) {
            U c0h, c0l, c1h, c1l;
#pragma unroll
            for (int j = 0; j < 8; ++j) split_f32(va[j],     c0h.hf[j], c0l.hf[j]);
#pragma unroll
            for (int j = 0; j < 8; ++j) split_f32(va[8 + j], c1h.hf[j], c1l.hf[j]);
            *(int4*)&Ah[nxt][2*h  ][lr][0] = c0h.v;
            *(int4*)&Ah[nxt][2*h+1][lr][0] = c1h.v;
            *(int4*)&Al[nxt][2*h  ][lr][0] = c0l.v;
            *(int4*)&Al[nxt][2*h+1][lr][0] = c1l.v;
        }
        __syncthreads();   // drains vmcnt (DMA) + lgkm (writes), all waves ready
        cur = nxt;
    }

#pragma unroll
    for (int tj = 0; tj < 4; ++tj) {
        const int o = bn*128 + nw*64 + tj*16 + l15;
        const float alpha = ab[o], beta = ab[256 + o];
#pragma unroll
        for (int ti = 0; ti < 4; ++ti) {
            const int m0 = bm*128 + mw*64 + ti*16 + quad*4;
#pragma unroll
            for (int r = 0; r < 4; ++r) {
                float c = accA[ti][tj][r] + accB[ti][tj][r] * (1.0f/2048.0f);
                float z = c * alpha + beta;
                _Float16 zh, zl;
                split_f32(z, zh, zl);
                const size_t off = (size_t)(m0 + r) * 256 + o;
                z1h[off] = zh;
                z1l[off] = zl;
            }
        }
    }
}

// ---------------------------------------------------------------------------
// K2: conv2 + bn2, fp16 2-limb MFMA GEMM. K=768 (dt*256+c), halo zero-fill.
// Same dbuf/1-barrier restructure; A reg-staged (halo select), B via DMA.
// ---------------------------------------------------------------------------
__global__ __launch_bounds__(256, 2) void conv2_mfma(
    const _Float16* __restrict__ z1h, const _Float16* __restrict__ z1l,
    const _Float16* __restrict__ w2h, const _Float16* __restrict__ w2l,
    const float* __restrict__ ab, float* __restrict__ z2)
{
    __shared__ _Float16 Ah[2][4][128][8];
    __shared__ _Float16 Al[2][4][128][8];
    __shared__ _Float16 Bh[2][4][128][8];
    __shared__ _Float16 Bl[2][4][128][8];

    const int tid = threadIdx.x;
    const int bm = blockIdx.x, bn = blockIdx.y;
    const int lr = tid & 127;
    const int h  = tid >> 7;

    const int am = bm * 128 + lr;
    const int an = am / 63, at = am - an * 63;
    const _Float16* abase_h = z1h + (size_t)an * 16128;
    const _Float16* abase_l = z1l + (size_t)an * 16128;

    const int lane = tid & 63;
    const int wv   = tid >> 6;
    const int mw   = wv & 1, nw = wv >> 1;
    const int quad = lane >> 4;
    const int l15  = lane & 15;

    const int q0 = wv >> 1;
    const int rh = (wv & 1) * 64;
    const _Float16* bh_g = w2h + (size_t)(bn * 128 + rh + lane) * 768;
    const _Float16* bl_g = w2l + (size_t)(bn * 128 + rh + lane) * 768;

    floatx4 accA[4][4] = {};
    floatx4 accB[4][4] = {};

    const int4 z4 = {0, 0, 0, 0};
    int4 a0h, a1h, a0l, a1l;

    auto loadA = [&](int it, int4& r0h, int4& r1h, int4& r0l, int4& r1l) {
        const int kap0 = it * 32;
        const int dt   = kap0 >> 8;
        const int c0   = kap0 & 255;
        const int trow = at + dt - 1;
        const bool valid = (trow >= 0) && (trow < 63);
        const _Float16* aph = abase_h + trow * 256 + c0 + h * 16;
        const _Float16* apl = abase_l + trow * 256 + c0 + h * 16;
        r0h = valid ? *(const int4*)(aph)     : z4;
        r1h = valid ? *(const int4*)(aph + 8) : z4;
        r0l = valid ? *(const int4*)(apl)     : z4;
        r1l = valid ? *(const int4*)(apl + 8) : z4;
    };

    // ---- prologue: stage tile 0 ----
    {
        loadA(0, a0h, a1h, a0l, a1l);
        lds_dma16(bh_g + q0 * 8,       &Bh[0][q0    ][rh][0]);
        lds_dma16(bh_g + (q0 + 2) * 8, &Bh[0][q0 + 2][rh][0]);
        lds_dma16(bl_g + q0 * 8,       &Bl[0][q0    ][rh][0]);
        lds_dma16(bl_g + (q0 + 2) * 8, &Bl[0][q0 + 2][rh][0]);
        *(int4*)&Ah[0][2*h  ][lr][0] = a0h;
        *(int4*)&Ah[0][2*h+1][lr][0] = a1h;
        *(int4*)&Al[0][2*h  ][lr][0] = a0l;
        *(int4*)&Al[0][2*h+1][lr][0] = a1l;
        __syncthreads();
    }

    int cur = 0;
    for (int it = 0; it < 24; ++it) {
        const int nxt = cur ^ 1;
        const bool pf = (it < 23);

        if (pf) {
            loadA(it + 1, a0h, a1h, a0l, a1l);
            const int ko = (it + 1) * 32;
            lds_dma16(bh_g + ko + q0 * 8,       &Bh[nxt][q0    ][rh][0]);
            lds_dma16(bh_g + ko + (q0 + 2) * 8, &Bh[nxt][q0 + 2][rh][0]);
            lds_dma16(bl_g + ko + q0 * 8,       &Bl[nxt][q0    ][rh][0]);
            lds_dma16(bl_g + ko + (q0 + 2) * 8, &Bl[nxt][q0 + 2][rh][0]);
        }

        half8 fah[4], fal[4], fbh[4], fbl[4];
#pragma unroll
        for (int t = 0; t < 4; ++t) {
            fah[t] = *(const half8*)&Ah[cur][quad][mw*64 + t*16 + l15][0];
            fal[t] = *(const half8*)&Al[cur][quad][mw*64 + t*16 + l15][0];
            fbh[t] = *(const half8*)&Bh[cur][quad][nw*64 + t*16 + l15][0];
            fbl[t] = *(const half8*)&Bl[cur][quad][nw*64 + t*16 + l15][0];
        }
#pragma unroll
        for (int ti = 0; ti < 4; ++ti)
#pragma unroll
            for (int tj = 0; tj < 4; ++tj) {
                accA[ti][tj] = __builtin_amdgcn_mfma_f32_16x16x32_f16(fah[ti], fbh[tj], accA[ti][tj], 0, 0, 0);
                accB[ti][tj] = __builtin_amdgcn_mfma_f32_16x16x32_f16(fah[ti], fbl[tj], accB[ti][tj], 0, 0, 0);
                accB[ti][tj] = __builtin_amdgcn_mfma_f32_16x16x32_f16(fal[ti], fbh[tj], accB[ti][tj], 0, 0, 0);
            }

        if (pf) {
            *(int4*)&Ah[nxt][2*h  ][lr][0] = a0h;
            *(int4*)&Ah[nxt][2*h+1][lr][0] = a1h;
            *(int4*)&Al[nxt][2*h  ][lr][0] = a0l;
            *(int4*)&Al[nxt][2*h+1][lr][0] = a1l;
        }
        __syncthreads();
        cur = nxt;
    }

#pragma unroll
    for (int tj = 0; tj < 4; ++tj) {
        const int o = bn*128 + nw*64 + tj*16 + l15;
        const float alpha = ab[o], beta = ab[256 + o];
#pragma unroll
        for (int ti = 0; ti < 4; ++ti) {
            const int m0 = bm*128 + mw*64 + ti*16 + quad*4;
#pragma unroll
            for (int r = 0; r < 4; ++r) {
                float c = accA[ti][tj][r] + accB[ti][tj][r] * (1.0f/2048.0f);
                z2[(size_t)(m0 + r) * 256 + o] = c * alpha + beta;
            }
        }
    }
}

// ---------------------------------------------------------------------------
// K3a: cuba1 — z2 [n][t][c] -> binary spikes s1 (fp16 {0,1}) in [n][t][c]
// ---------------------------------------------------------------------------
__global__ __launch_bounds__(256) void cuba1_kernel(
    const float* __restrict__ z2, _Float16* __restrict__ s1)
{
    const int n   = blockIdx.x;
    const int tid = threadIdx.x;
    const float* zrow = z2 + (size_t)n * 16128 + tid;
    _Float16*    srow = s1 + (size_t)n * 16128 + tid;
    float cur = 0.f, vol = 0.f;
    for (int t = 0; t < 63; ++t) {
        float xv = zrow[(size_t)t * 256];
        cur = 0.1f * cur + xv;
        vol = 0.1f * vol + cur;
        bool sp = (vol - 0.3f) >= 0.f;
        srow[(size_t)t * 256] = sp ? (_Float16)1.0f : (_Float16)0.0f;
        if (sp) vol = 0.f;
    }
}

// ---------------------------------------------------------------------------
// K3b: dense1 via MFMA. M=32256, K=256, N=256. A binary fp16, B 2-limb.
// Fully DMA-staged (no reg staging, no in-loop VALU), dbuf, 1 barrier/iter.
// ---------------------------------------------------------------------------
__global__ __launch_bounds__(256, 2) void dense1_mfma(
    const _Float16* __restrict__ s1,
    const _Float16* __restrict__ wdh, const _Float16* __restrict__ wdl,
    float* __restrict__ y1)
{
    __shared__ _Float16 As[2][4][128][8];
    __shared__ _Float16 Bh[2][4][128][8];
    __shared__ _Float16 Bl[2][4][128][8];

    const int tid = threadIdx.x;
    const int bm = blockIdx.x, bn = blockIdx.y;

    const int lane = tid & 63;
    const int wv   = tid >> 6;
    const int mw   = wv & 1, nw = wv >> 1;
    const int quad = lane >> 4;
    const int l15  = lane & 15;

    const int q0 = wv >> 1;
    const int rh = (wv & 1) * 64;
    const _Float16* a_g  = s1  + (size_t)(bm * 128 + rh + lane) * 256;
    const _Float16* bh_g = wdh + (size_t)(bn * 128 + rh + lane) * 256;
    const _Float16* bl_g = wdl + (size_t)(bn * 128 + rh + lane) * 256;

    floatx4 accA[4][4] = {};
    floatx4 accB[4][4] = {};

    // ---- prologue ----
    {
        lds_dma16(a_g  + q0 * 8,       &As[0][q0    ][rh][0]);
        lds_dma16(a_g  + (q0 + 2) * 8, &As[0][q0 + 2][rh][0]);
        lds_dma16(bh_g + q0 * 8,       &Bh[0][q0    ][rh][0]);
        lds_dma16(bh_g + (q0 + 2) * 8, &Bh[0][q0 + 2][rh][0]);
        lds_dma16(bl_g + q0 * 8,       &Bl[0][q0    ][rh][0]);
        lds_dma16(bl_g + (q0 + 2) * 8, &Bl[0][q0 + 2][rh][0]);
        __syncthreads();
    }

    int cur = 0;
    for (int it = 0; it < 8; ++it) {
        const int nxt = cur ^ 1;
        const bool pf = (it < 7);

        if (pf) {
            const int ko = (it + 1) * 32;
            lds_dma16(a_g  + ko + q0 * 8,       &As[nxt][q0    ][rh][0]);
            lds_dma16(a_g  + ko + (q0 + 2) * 8, &As[nxt][q0 + 2][rh][0]);
            lds_dma16(bh_g + ko + q0 * 8,       &Bh[nxt][q0    ][rh][0]);
            lds_dma16(bh_g + ko + (q0 + 2) * 8, &Bh[nxt][q0 + 2][rh][0]);
            lds_dma16(bl_g + ko + q0 * 8,       &Bl[nxt][q0    ][rh][0]);
            lds_dma16(bl_g + ko + (q0 + 2) * 8, &Bl[nxt][q0 + 2][rh][0]);
        }

        half8 fa[4], fbh[4], fbl[4];
#pragma unroll
        for (int t = 0; t < 4; ++t) {
            fa[t]  = *(const half8*)&As[cur][quad][mw*64 + t*16 + l15][0];
            fbh[t] = *(const half8*)&Bh[cur][quad][nw*64 + t*16 + l15][0];
            fbl[t] = *(const half8*)&Bl[cur][quad][nw*64 + t*16 + l15][0];
        }
#pragma unroll
        for (int ti = 0; ti < 4; ++ti)
#pragma unroll
            for (int tj = 0; tj < 4; ++tj) {
                accA[ti][tj] = __builtin_amdgcn_mfma_f32_16x16x32_f16(fa[ti], fbh[tj], accA[ti][tj], 0, 0, 0);
                accB[ti][tj] = __builtin_amdgcn_mfma_f32_16x16x32_f16(fa[ti], fbl[tj], accB[ti][tj], 0, 0, 0);
            }

        __syncthreads();
        cur = nxt;
    }

#pragma unroll
    for (int tj = 0; tj < 4; ++tj) {
        const int o = bn*128 + nw*64 + tj*16 + l15;
#pragma unroll
        for (int ti = 0; ti < 4; ++ti) {
            const int m0 = bm*128 + mw*64 + ti*16 + quad*4;
#pragma unroll
            for (int r = 0; r < 4; ++r)
                y1[(size_t)(m0 + r) * 256 + o] =
                    accA[ti][tj][r] + accB[ti][tj][r] * (1.0f/2048.0f);
        }
    }
}

// ---------------------------------------------------------------------------
// K3c: cuba2 (per (n,o) over t) -> spike masks -> dense2 -> cuba3 -> out
// ---------------------------------------------------------------------------
__global__ __launch_bounds__(256) void snn_tail(
    const float* __restrict__ y1, const float* __restrict__ w2,
    float* __restrict__ out)
{
    __shared__ unsigned long long M2[256];
    __shared__ float Y[2 * 63];
    const int n   = blockIdx.x;
    const int tid = threadIdx.x;

    {
        const float* yrow = y1 + (size_t)n * 16128 + tid;
        float v = 0.f;
        unsigned long long mask2 = 0ull;
        for (int t = 0; t < 63; ++t) {
            float yv = yrow[(size_t)t * 256];
            v = 0.9f * v + yv;                 // cd=0 -> i = x
            if ((v - 0.1f) >= 0.f) { mask2 |= (1ull << t); v = 0.f; }
        }
        M2[tid] = mask2;
    }
    __syncthreads();

    if (tid < 126) {
        const int cls = tid / 63;
        const int t   = tid - cls * 63;
        const float* wrow = w2 + cls * 256;
        float acc = 0.f;
#pragma unroll 4
        for (int o = 0; o < 256; ++o)
            acc += ((M2[o] >> t) & 1ull) ? wrow[o] : 0.f;
        Y[cls * 63 + t] = acc;
    }
    __syncthreads();
    if (tid < 2) {
        float v = 0.f;
        float* orow = out + (size_t)n * 126 + tid * 63;
        for (int t = 0; t < 63; ++t) {
            v = 0.9f * v + Y[tid * 63 + t];
            float u = v - 0.1f;
            float s = (u >= 0.f) ? 1.f : 0.f;
            orow[t] = s;
            v = (u >= 0.f) ? 0.f : v;
        }
    }
}

// ---------------------------------------------------------------------------
extern "C" void kernel_launch(void* const* d_in, const int* in_sizes, int n_in,
                              void* d_out, int out_size, void* d_ws, size_t ws_size,
                              hipStream_t stream)
{
    const float* x    = (const float*)d_in[0];
    const float* c1w  = (const float*)d_in[1];
    const float* c1b  = (const float*)d_in[2];
    const float* g1   = (const float*)d_in[3];
    const float* b1   = (const float*)d_in[4];
    const float* m1   = (const float*)d_in[5];
    const float* v1   = (const float*)d_in[6];
    const float* c2w  = (const float*)d_in[7];
    const float* c2b  = (const float*)d_in[8];
    const float* g2   = (const float*)d_in[9];
    const float* b2   = (const float*)d_in[10];
    const float* m2   = (const float*)d_in[11];
    const float* v2   = (const float*)d_in[12];
    const float* w1   = (const float*)d_in[13];
    const float* w2   = (const float*)d_in[14];
    float* out = (float*)d_out;

    float* ws = (float*)d_ws;
    // region A: z1 limbs during conv; reused as y1 (fp32) after conv2
    float*    zA  = ws;                               // 8,257,536 f
    _Float16* z1h = (_Float16*)zA;
    _Float16* z1l = (_Float16*)(zA + 4128768);
    float*    y1  = zA;
    float*    z2  = zA + 8257536;                     // 8,257,536 f
    _Float16* s1  = (_Float16*)(z2 + 8257536);        // 4,128,768 f
    float*    wsp = z2 + 8257536 + 4128768;
    _Float16* w1h = (_Float16*)wsp;                   // 262,144 f
    _Float16* w1l = (_Float16*)(wsp + 262144);        // 262,144 f
    _Float16* w2h = (_Float16*)(wsp + 2*262144);                    //  98,304 f
    _Float16* w2l = (_Float16*)(wsp + 2*262144 + 98304);            //  98,304 f
    _Float16* wdh = (_Float16*)(wsp + 2*262144 + 2*98304);          //  32,768 f
    _Float16* wdl = (_Float16*)(wsp + 2*262144 + 2*98304 + 32768);  //  32,768 f
    float*    ab1 = wsp + 2*262144 + 2*98304 + 2*32768;
    float*    ab2 = ab1 + 512;

    prep_kernel<<<256, 256, 0, stream>>>(c1w, c1b, g1, b1, m1, v1,
                                         c2w, c2b, g2, b2, m2, v2,
                                         w1, w1h, w1l, w2h, w2l, wdh, wdl,
                                         ab1, ab2);
    conv1_mfma<<<dim3(252, 2), 256, 0, stream>>>(x, w1h, w1l, ab1, z1h, z1l);
    conv2_mfma<<<dim3(252, 2), 256, 0, stream>>>(z1h, z1l, w2h, w2l, ab2, z2);
    cuba1_kernel<<<512, 256, 0, stream>>>(z2, s1);
    dense1_mfma<<<dim3(252, 2), 256, 0, stream>>>(s1, wdh, wdl, y1);
    snn_tail<<<512, 256, 0, stream>>>(y1, w2, out);
}